// Round 8
// baseline (331.071 us; speedup 1.0000x reference)
//
#include <hip/hip_runtime.h>
#include <math.h>

#define NXY    192
#define CELLS  (NXY*NXY)
#define NBATCH 4
#define NSTEPS 256
#define TCH    16                // steps per chunk (= halo width both dims)
#define NCHUNK (NSTEPS/TCH)      // 16
#define NP     20                // v2f col-packs per lane (40 cols in window)
#define NSTRIP 24                // col strips, 8 out cols each
#define NBAND  6                 // row bands, 32 out rows each (64-row window)
#define NBLKS  (NBATCH*NBAND*NSTRIP)   // 576 single-wave blocks

// workspace layout (float offsets); state arrays TRANSPOSED: idx = col*NXY + row
#define K3_OFF (16*CELLS)
#define Q_OFF  (K3_OFF + CELLS)
#define I_OFF  (Q_OFF + CELLS)

typedef float v2f __attribute__((ext_vector_type(2)));

__device__ __forceinline__ float dpp_up1(float v) {   // lane i <- lane i-1 (row above)
    int r = __builtin_amdgcn_update_dpp(0, __builtin_bit_cast(int, v),
                                        0x138, 0xf, 0xf, true); // wave_shr:1
    return __builtin_bit_cast(float, r);
}
__device__ __forceinline__ float dpp_dn1(float v) {   // lane i <- lane i+1 (row below)
    int r = __builtin_amdgcn_update_dpp(0, __builtin_bit_cast(int, v),
                                        0x130, 0xf, 0xf, true); // wave_shl:1
    return __builtin_bit_cast(float, r);
}

__device__ __forceinline__ float pml_prof(int i) {
    int t;
    if (i <= 20)            t = 20 - i;
    else if (i >= NXY - 21) t = i - (NXY - 21);
    else                    return 0.0f;
    float u  = (float)t * 0.05f;
    float u2 = u * u;
    return 3.0f * u2 * u2;
}

__global__ void setup_k(const float* __restrict__ rho, float* __restrict__ ws) {
    int idx    = blockIdx.x * blockDim.x + threadIdx.x;
    int stride = gridDim.x * blockDim.x;
    for (int k = idx; k < 8 * CELLS; k += stride) ws[k] = 0.0f;   // parity-0 state
    const float IH2 = (float)(1.0 / (2.01 * 2.01));
    for (int k = idx; k < CELLS; k += stride) {
        int i = k % NXY;          // row   (k is the TRANSPOSED index col*NXY+row)
        int j = k / NXY;          // col
        int kr = i * NXY + j;     // row-major index into rho
        float r0 = rho[kr];
        float ru = (i > 0)       ? rho[kr - NXY] : 0.0f;
        float rd = (i < NXY - 1) ? rho[kr + NXY] : 0.0f;
        float rl = (j > 0)       ? rho[kr - 1]   : 0.0f;
        float rr2 = (j < NXY - 1) ? rho[kr + 1]  : 0.0f;
        float lpf = 0.5f * r0 + 0.125f * ((ru + rd) + (rl + rr2));
        float p   = 0.5f * (1.0f + tanhf(100.0f * (lpf - 0.5f)));
        float c   = 1.0f - 0.1f * p;
        float c2h = c * c * IH2;
        float bx = pml_prof(i), by = pml_prof(j);
        float bb = sqrtf(bx * bx + by * by);
        float a1 = 1.0f / (1.0f + 0.5f * bb);
        ws[K3_OFF + k] = a1 * c2h;        // K  (transposed)
        ws[Q_OFF  + k] = 1.0f - 2.0f * a1; // Q  (transposed)
    }
    if (idx < 12) ws[I_OFF + idx] = 0.0f;
}

__global__ __launch_bounds__(64, 1)
void chunk_k(const float* __restrict__ x, float* __restrict__ ws, int chunk) {
    int blk = blockIdx.x;
    int b  = blk / (NBAND * NSTRIP);
    int r  = blk % (NBAND * NSTRIP);
    int bi = r / NSTRIP, sj = r % NSTRIP;
    int row0 = 32 * bi - 16;           // window row origin (64 rows)
    int col0 = 8  * sj - 16;           // window col origin (40 cols)
    int l  = threadIdx.x;              // lane = row
    int gi = row0 + l;
    bool rok = (gi >= 0 && gi < NXY);

    const float* kg = ws + K3_OFF;
    const float* qg = ws + Q_OFF;
    int pin = chunk & 1, pout = pin ^ 1;
    const float* curg  = ws + ((pin  * 2 + 0) * NBATCH + b) * CELLS;
    const float* prvg  = ws + ((pin  * 2 + 1) * NBATCH + b) * CELLS;
    float*       ncurg = ws + ((pout * 2 + 0) * NBATCH + b) * CELLS;
    float*       nprvg = ws + ((pout * 2 + 1) * NBATCH + b) * CELLS;

    // per-lane state: 4 arrays x 20 v2f = 160 VGPR
    v2f yc[NP], yp[NP], Ka[NP], Qa[NP];
#pragma unroll
    for (int j = 0; j < NP; j++) {
        int c0 = col0 + 2 * j;
        int i0 = c0 * NXY + gi;              // transposed: coalesced across lanes
        bool ok0 = rok && c0 >= 0 && c0 < NXY;
        bool ok1 = rok && (c0 + 1) >= 0 && (c0 + 1) < NXY;
        v2f kv = {0.f,0.f}, qv = {0.f,0.f}, cv = {0.f,0.f}, pv = {0.f,0.f};
        if (ok0) { kv.x = kg[i0]; qv.x = qg[i0];
                   cv.x = curg[i0]; pv.x = prvg[i0]; }
        if (ok1) { kv.y = kg[i0 + NXY]; qv.y = qg[i0 + NXY];
                   cv.y = curg[i0 + NXY]; pv.y = prvg[i0 + NXY]; }
        Ka[j] = kv; Qa[j] = qv; yc[j] = cv; yp[j] = pv;
    }
    // out-of-domain cells: K=Q=0 -> yn = c = 0 forever (Dirichlet zero)  ✓

    // source (40,96): blocks sj in [10,14] have col 96 at pack js (.x comp);
    // row 40 in window only for bands 0,1
    bool has_src = (sj >= 10 && sj <= 14) && (40 >= row0 && 40 < row0 + 64);
    int  js   = 56 - 4 * sj;                       // (96-col0)/2
    float srcm = (l == 40 - row0) ? 1.f : 0.f;

    // probes (160, 48*(p+1)): band 5 (row 160 = lane 16), strips 6/12/18 ->
    // probe col is always pack 8 .x
    bool has_prb = (bi == 5) && (sj == 6 || sj == 12 || sj == 18);
    float prbm = (l == 16) ? 1.f : 0.f;
    float pacc = 0.f;

    int xbase = b * NSTEPS + chunk * TCH;

// row update per col-pack: yn = c + Q*(p-c) + K*(S-4c)
// vertical = DPP (lane +/-1), horizontal = register neighbors
#define STEP(CUR, PRV, SIDX) do {                                              \
    float xs = x[xbase + (SIDX)];                                              \
    _Pragma("unroll")                                                          \
    for (int j = 0; j < NP; j++) {                                             \
        v2f cv = CUR[j];                                                       \
        v2f up, dn, hz;                                                        \
        up.x = dpp_up1(cv.x); up.y = dpp_up1(cv.y);                            \
        dn.x = dpp_dn1(cv.x); dn.y = dpp_dn1(cv.y);                            \
        hz.x = (j > 0      ? CUR[j - 1].y : 0.f) + cv.y;                       \
        hz.y = (j < NP - 1 ? CUR[j + 1].x : 0.f) + cv.x;                       \
        v2f S  = (up + dn) + hz;                                               \
        v2f t  = PRV[j] - cv;                                                  \
        v2f u  = S - 4.0f * cv;                                                \
        v2f yn = cv + Qa[j] * t + Ka[j] * u;                                   \
        if (has_src && j == js) yn.x += srcm * xs;                             \
        if (has_prb && j == 8)  { float q = prbm * yn.x; pacc += q * yn.x; }   \
        PRV[j] = yn;                                                           \
    }                                                                          \
} while (0)

#pragma unroll 1
    for (int s2 = 0; s2 < TCH / 2; s2++) {
        STEP(yc, yp, 2 * s2);        // new cur -> yp
        STEP(yp, yc, 2 * s2 + 1);    // new cur -> yc
    }
#undef STEP
    // after 16 steps: yc = y(t_end) valid on rows [16,48) x packs [8,12);
    // yp = y(t_end-1) valid at least there too

    // store out-tile: rows lanes 16..47, cols packs 8..11 (transposed, coalesced)
    if (l >= 16 && l < 48) {
#pragma unroll
        for (int j = 8; j < 12; j++) {
            int c0 = col0 + 2 * j;           // in [8sj, 8sj+8) — always in-domain
            int i0 = c0 * NXY + gi;
            ncurg[i0]       = yc[j].x;
            ncurg[i0 + NXY] = yc[j].y;
            nprvg[i0]       = yp[j].x;
            nprvg[i0 + NXY] = yp[j].y;
        }
    }
    if (has_prb && l == 16) ws[I_OFF + b * 3 + (sj / 6 - 1)] += pacc;
}

__global__ void final_k(const float* __restrict__ ws, float* __restrict__ out) {
    int t = threadIdx.x;
    if (t < 12) {
        const float* I = ws + I_OFF;
        int b = t / 3;
        float s = I[3 * b] + I[3 * b + 1] + I[3 * b + 2];
        out[t] = I[t] / s;
    }
}

extern "C" void kernel_launch(void* const* d_in, const int* in_sizes, int n_in,
                              void* d_out, int out_size, void* d_ws, size_t ws_size,
                              hipStream_t stream) {
    const float* x   = (const float*)d_in[0];   // (4,256) fp32
    const float* rho = (const float*)d_in[1];   // (192,192) fp32
    float* ws  = (float*)d_ws;
    float* out = (float*)d_out;

    setup_k<<<256, 256, 0, stream>>>(rho, ws);
    for (int c = 0; c < NCHUNK; c++)
        chunk_k<<<NBLKS, 64, 0, stream>>>(x, ws, c);
    final_k<<<1, 64, 0, stream>>>(ws, out);
}

// Round 9
// 312.161 us; speedup vs baseline: 1.0606x; 1.0606x over previous
//
#include <hip/hip_runtime.h>
#include <math.h>

#define NXY    192
#define CELLS  (NXY*NXY)
#define NBATCH 4
#define NSTEPS 256
#define TCH    16                 // steps per chunk (= vertical halo)
#define NCHUNK (NSTEPS/TCH)       // 16
#define TPB    256                // 4 waves
#define NW     4
#define RPW    10                 // rows per wave
#define WIN    40                 // window rows = OB + 2*TCH
#define OB     8                  // out-band rows
#define NBAND  24                 // 192/8
#define NBLKS  (NBATCH*NBAND)     // 96 blocks
// lane owns cols 3l..3l+2 -> 64 lanes cover ALL 192 cols: no horizontal halo

// workspace layout (float offsets)
#define K3_OFF (16*CELLS)
#define Q_OFF  (K3_OFF + CELLS)
#define I_OFF  (Q_OFF + CELLS)

__device__ __forceinline__ float dpp_up1(float v) {   // lane i <- lane i-1
    int r = __builtin_amdgcn_update_dpp(0, __builtin_bit_cast(int, v),
                                        0x138, 0xf, 0xf, true); // wave_shr:1
    return __builtin_bit_cast(float, r);
}
__device__ __forceinline__ float dpp_dn1(float v) {   // lane i <- lane i+1
    int r = __builtin_amdgcn_update_dpp(0, __builtin_bit_cast(int, v),
                                        0x130, 0xf, 0xf, true); // wave_shl:1
    return __builtin_bit_cast(float, r);
}

__device__ __forceinline__ float pml_prof(int i) {
    int t;
    if (i <= 20)            t = 20 - i;
    else if (i >= NXY - 21) t = i - (NXY - 21);
    else                    return 0.0f;
    float u  = (float)t * 0.05f;
    float u2 = u * u;
    return 3.0f * u2 * u2;
}

__global__ void setup_k(const float* __restrict__ rho, float* __restrict__ ws) {
    int idx    = blockIdx.x * blockDim.x + threadIdx.x;
    int stride = gridDim.x * blockDim.x;
    for (int k = idx; k < 8 * CELLS; k += stride) ws[k] = 0.0f;  // parity-0 state
    const float IH2 = (float)(1.0 / (2.01 * 2.01));
    for (int k = idx; k < CELLS; k += stride) {
        int i = k / NXY, j = k % NXY;
        float r0 = rho[k];
        float ru = (i > 0)       ? rho[k - NXY] : 0.0f;
        float rd = (i < NXY - 1) ? rho[k + NXY] : 0.0f;
        float rl = (j > 0)       ? rho[k - 1]   : 0.0f;
        float rr2 = (j < NXY - 1) ? rho[k + 1]  : 0.0f;
        float lpf = 0.5f * r0 + 0.125f * ((ru + rd) + (rl + rr2));
        float p   = 0.5f * (1.0f + tanhf(100.0f * (lpf - 0.5f)));
        float c   = 1.0f - 0.1f * p;
        float c2h = c * c * IH2;
        float bx = pml_prof(i), by = pml_prof(j);
        float bb = sqrtf(bx * bx + by * by);
        float a1 = 1.0f / (1.0f + 0.5f * bb);
        ws[K3_OFF + k] = a1 * c2h;         // K
        ws[Q_OFF  + k] = 1.0f - 2.0f * a1; // Q
    }
    if (idx < 12) ws[I_OFF + idx] = 0.0f;
}

__global__ __launch_bounds__(TPB, 1)
void chunk_k(const float* __restrict__ x, float* __restrict__ ws, int chunk) {
    int blk = blockIdx.x;
    int b  = blk / NBAND;
    int bi = blk % NBAND;
    int I0 = OB * bi - TCH;          // window row origin (40 rows)
    int t  = threadIdx.x;
    int w  = t >> 6;                 // wave 0..3, owns window rows [10w,10w+10)
    int l  = t & 63;                 // lane: cols 3l..3l+2 (whole grid width)
    int row0w = I0 + RPW * w;
    int j0 = 3 * l;

    // wave-boundary ghosts: [parity][top/bot][slot 0..5][lane]
    // wave w writes slot w+1; reads up from slot w, down from slot w+2;
    // slots 0 and 5 stay zero (rows outside window)
    __shared__ float2 hA[2][2][NW + 2][64];  // c0,c1
    __shared__ float  hB[2][2][NW + 2][64];  // c2
    __shared__ float  xs_l[TCH];
    for (int k = t; k < 2 * 2 * (NW + 2) * 64; k += TPB) {
        ((float2*)hA)[k] = make_float2(0.f, 0.f);
        ((float*)hB)[k]  = 0.f;
    }
    if (t < TCH) xs_l[t] = x[b * NSTEPS + chunk * TCH + t];

    const float* kg = ws + K3_OFF;
    const float* qg = ws + Q_OFF;
    int pin = chunk & 1, pout = pin ^ 1;
    const float* curg  = ws + ((pin  * 2 + 0) * NBATCH + b) * CELLS;
    const float* prvg  = ws + ((pin  * 2 + 1) * NBATCH + b) * CELLS;
    float*       ncurg = ws + ((pout * 2 + 0) * NBATCH + b) * CELLS;
    float*       nprvg = ws + ((pout * 2 + 1) * NBATCH + b) * CELLS;

    // per-lane state: 4 arrays x 10 rows x 3 cols = 120 VGPR
    float yc[RPW][3], yp[RPW][3], Ka[RPW][3], Qa[RPW][3];
#pragma unroll
    for (int r = 0; r < RPW; r++) {
        int gi = row0w + r;
        bool ok = (gi >= 0 && gi < NXY);
        int base = gi * NXY + j0;
#pragma unroll
        for (int k = 0; k < 3; k++) {
            if (ok) {
                Ka[r][k] = kg[base + k];
                Qa[r][k] = qg[base + k];
                yc[r][k] = curg[base + k];
                yp[r][k] = prvg[base + k];
            } else {  // out-of-domain row: K=Q=0 -> stays 0 forever
                Ka[r][k] = 0.f; Qa[r][k] = 0.f; yc[r][k] = 0.f; yp[r][k] = 0.f;
            }
        }
    }

    // source (40,96): window row 40-I0; col 96 = lane 32, c0
    int srw = 40 - I0;
    bool wave_src = (srw >= RPW * w) && (srw < RPW * w + RPW);
    int src_rl = srw - RPW * w;
    float srcm = (l == 32) ? 1.f : 0.f;

    // probes (160, {48,96,144}): row 160 -> bi==20, window row 16, wave 1, r=6;
    // cols = 3*{16,32,48} -> lanes 16/32/48, c0
    bool has_prb = (bi == 20) && (w == 1);
    const int prb_rl = 6;
    float prbm = (l == 16 || l == 32 || l == 48) ? 1.f : 0.f;
    float pacc = 0.f;

// 3-cell row update: yn = c + Q*(p-c) + K*(S-4c); only 2 wave-DPP per row
#define ROWC(CUR, PRV, r_, U0, U1, U2, D0, D1, D2) do {                        \
    float c0 = CUR[r_][0], c1 = CUR[r_][1], c2 = CUR[r_][2];                   \
    float L = dpp_up1(c2);   /* col 3l-1 (lane0 -> 0 = Dirichlet) */           \
    float R = dpp_dn1(c0);   /* col 3l+3 (lane63 -> 0 = Dirichlet) */          \
    float S0 = ((U0) + (D0)) + (L + c1);                                       \
    float S1 = ((U1) + (D1)) + (c0 + c2);                                      \
    float S2 = ((U2) + (D2)) + (c1 + R);                                       \
    float y0 = c0 + Qa[r_][0] * (PRV[r_][0] - c0) + Ka[r_][0] * (S0 - 4.f*c0); \
    float y1 = c1 + Qa[r_][1] * (PRV[r_][1] - c1) + Ka[r_][1] * (S1 - 4.f*c1); \
    float y2 = c2 + Qa[r_][2] * (PRV[r_][2] - c2) + Ka[r_][2] * (S2 - 4.f*c2); \
    if (wave_src && (r_) == src_rl) y0 += srcm * xsv;                          \
    if (has_prb && (r_) == prb_rl) { float q = prbm * y0; pacc += q * y0; }    \
    PRV[r_][0] = y0; PRV[r_][1] = y1; PRV[r_][2] = y2;                         \
} while (0)

// self-contained step: write current boundaries, barrier, read ghosts, compute
#define STEP(CUR, PRV, PH, SIDX) do {                                          \
    hA[PH][0][w + 1][l] = make_float2(CUR[0][0], CUR[0][1]);                   \
    hB[PH][0][w + 1][l] = CUR[0][2];                                           \
    hA[PH][1][w + 1][l] = make_float2(CUR[9][0], CUR[9][1]);                   \
    hB[PH][1][w + 1][l] = CUR[9][2];                                           \
    __syncthreads();                                                           \
    float2 ua = hA[PH][1][w][l];     float ub = hB[PH][1][w][l];               \
    float2 da = hA[PH][0][w + 2][l]; float db = hB[PH][0][w + 2][l];           \
    float xsv = xs_l[SIDX];                                                    \
    ROWC(CUR, PRV, 0, ua.x, ua.y, ub, CUR[1][0], CUR[1][1], CUR[1][2]);        \
    _Pragma("unroll")                                                          \
    for (int r = 1; r <= 8; r++)                                               \
        ROWC(CUR, PRV, r, CUR[r-1][0], CUR[r-1][1], CUR[r-1][2],               \
             CUR[r+1][0], CUR[r+1][1], CUR[r+1][2]);                           \
    ROWC(CUR, PRV, 9, CUR[8][0], CUR[8][1], CUR[8][2], da.x, da.y, db);        \
} while (0)

#pragma unroll 1
    for (int s2 = 0; s2 < TCH / 2; s2++) {
        STEP(yc, yp, 0, 2 * s2);        // new cur -> yp
        STEP(yp, yc, 1, 2 * s2 + 1);    // new cur -> yc
    }
#undef STEP
#undef ROWC
    // yc = y(t_end), yp = y(t_end-1); valid on window rows [16,24) = out-band

    // store out-band rows [8bi, 8bi+8) — full 192-col rows, all lanes active
#pragma unroll
    for (int r = 0; r < RPW; r++) {
        int gi = row0w + r;
        if (gi >= OB * bi && gi < OB * bi + OB) {
            int base = gi * NXY + j0;
#pragma unroll
            for (int k = 0; k < 3; k++) {
                ncurg[base + k] = yc[r][k];
                nprvg[base + k] = yp[r][k];
            }
        }
    }
    // unique writer per (b, pid): only bi==20 block, lanes 16/32/48 of wave 1
    if (has_prb && (l == 16 || l == 32 || l == 48))
        ws[I_OFF + b * 3 + ((l >> 4) - 1)] += pacc;
}

__global__ void final_k(const float* __restrict__ ws, float* __restrict__ out) {
    int t = threadIdx.x;
    if (t < 12) {
        const float* I = ws + I_OFF;
        int b = t / 3;
        float s = I[3 * b] + I[3 * b + 1] + I[3 * b + 2];
        out[t] = I[t] / s;
    }
}

extern "C" void kernel_launch(void* const* d_in, const int* in_sizes, int n_in,
                              void* d_out, int out_size, void* d_ws, size_t ws_size,
                              hipStream_t stream) {
    const float* x   = (const float*)d_in[0];   // (4,256) fp32
    const float* rho = (const float*)d_in[1];   // (192,192) fp32
    float* ws  = (float*)d_ws;
    float* out = (float*)d_out;

    setup_k<<<256, 256, 0, stream>>>(rho, ws);
    for (int c = 0; c < NCHUNK; c++)
        chunk_k<<<NBLKS, TPB, 0, stream>>>(x, ws, c);
    final_k<<<1, 64, 0, stream>>>(ws, out);
}

// Round 10
// 201.438 us; speedup vs baseline: 1.6435x; 1.5497x over previous
//
#include <hip/hip_runtime.h>
#include <math.h>

#define NXY    192
#define CELLS  (NXY*NXY)
#define NBATCH 4
#define NSTEPS 256
#define TCH    16                 // steps per chunk (= halo radius)
#define NCHUNK (NSTEPS/TCH)       // 16
#define TPB    512                // 8 waves -> 2 waves/SIMD
#define NW     8
#define RPL    5                  // rows per wave (40-row window / 8 waves)
#define OUTR   6                  // out rows per tile
#define NBLKS  256                // 32 row-tiles x 2 col-tiles x 4 batches
// in-tile 128 cols x 40 rows; out-tile 96 cols x 6 rows (window rows [17,23))

// workspace layout (float offsets)
#define K3_OFF (16*CELLS)
#define Q_OFF  (K3_OFF + CELLS)
#define I_OFF  (Q_OFF + CELLS)

typedef float v2f __attribute__((ext_vector_type(2)));

__device__ __forceinline__ float dpp_up1(float v) {   // lane i <- lane i-1
    int r = __builtin_amdgcn_update_dpp(0, __builtin_bit_cast(int, v),
                                        0x138, 0xf, 0xf, true); // wave_shr:1
    return __builtin_bit_cast(float, r);
}
__device__ __forceinline__ float dpp_dn1(float v) {   // lane i <- lane i+1
    int r = __builtin_amdgcn_update_dpp(0, __builtin_bit_cast(int, v),
                                        0x130, 0xf, 0xf, true); // wave_shl:1
    return __builtin_bit_cast(float, r);
}

__device__ __forceinline__ float pml_prof(int i) {
    int t;
    if (i <= 20)            t = 20 - i;
    else if (i >= NXY - 21) t = i - (NXY - 21);
    else                    return 0.0f;
    float u  = (float)t * 0.05f;
    float u2 = u * u;
    return 3.0f * u2 * u2;
}

__global__ void setup_k(const float* __restrict__ rho, float* __restrict__ ws) {
    int idx    = blockIdx.x * blockDim.x + threadIdx.x;
    int stride = gridDim.x * blockDim.x;
    for (int k = idx; k < 8 * CELLS; k += stride) ws[k] = 0.0f;  // parity-0 state
    const float IH2 = (float)(1.0 / (2.01 * 2.01));
    for (int k = idx; k < CELLS; k += stride) {
        int i = k / NXY, j = k % NXY;
        float r0 = rho[k];
        float ru = (i > 0)       ? rho[k - NXY] : 0.0f;
        float rd = (i < NXY - 1) ? rho[k + NXY] : 0.0f;
        float rl = (j > 0)       ? rho[k - 1]   : 0.0f;
        float rr2 = (j < NXY - 1) ? rho[k + 1]  : 0.0f;
        float lpf = 0.5f * r0 + 0.125f * ((ru + rd) + (rl + rr2));
        float p   = 0.5f * (1.0f + tanhf(100.0f * (lpf - 0.5f)));
        float c   = 1.0f - 0.1f * p;
        float c2h = c * c * IH2;
        float bx = pml_prof(i), by = pml_prof(j);
        float bb = sqrtf(bx * bx + by * by);
        float a1 = 1.0f / (1.0f + 0.5f * bb);
        ws[K3_OFF + k] = a1 * c2h;         // K
        ws[Q_OFF  + k] = 1.0f - 2.0f * a1; // Q
    }
    if (idx < 12) ws[I_OFF + idx] = 0.0f;
}

__global__ __launch_bounds__(TPB, 1)
void chunk_k(const float* __restrict__ x, float* __restrict__ ws, int chunk) {
    int blk = blockIdx.x;
    int b  = blk / 64;                // batch
    int r_ = blk % 64;
    int bi = r_ >> 1, cj = r_ & 1;    // 32 row-tiles x 2 col-tiles
    int I0 = OUTR * bi - 17;          // window row origin (40 rows)
    int J0 = 96 * cj - 16;            // window col origin (128 cols)
    int t  = threadIdx.x;
    int w  = t >> 6;                  // wave 0..7, owns window rows [5w,5w+5)
    int l  = t & 63;                  // lane: local cols 2l, 2l+1
    int row0 = I0 + RPL * w;
    int gj   = J0 + 2 * l;

    // [parity][top/bot][slot 0..9][lane]; wave w writes slot w+1;
    // reads up from slot w, down from slot w+2; slots 0,9 stay zero.
    __shared__ v2f hb[2][2][NW + 2][64];
    for (int k = t; k < 2 * 2 * (NW + 2) * 64; k += TPB)
        ((v2f*)hb)[k] = (v2f){0.f, 0.f};

    // source amplitudes for this chunk -> registers (compile-time indexed)
    float xv[TCH];
    int xbase = b * NSTEPS + chunk * TCH;
#pragma unroll
    for (int i = 0; i < TCH; i++) xv[i] = x[xbase + i];

    const float* kg = ws + K3_OFF;
    const float* qg = ws + Q_OFF;
    int pin = chunk & 1, pout = pin ^ 1;
    const float* curg  = ws + ((pin  * 2 + 0) * NBATCH + b) * CELLS;
    const float* prvg  = ws + ((pin  * 2 + 1) * NBATCH + b) * CELLS;
    float*       ncurg = ws + ((pout * 2 + 0) * NBATCH + b) * CELLS;
    float*       nprvg = ws + ((pout * 2 + 1) * NBATCH + b) * CELLS;

    // per-lane state: 4 v2f arrays x 5 rows = 40 VGPRs
    v2f yc[RPL], yp[RPL], Qa[RPL], Ka[RPL];
    bool cok = (gj >= 0 && gj < NXY);
#pragma unroll
    for (int r = 0; r < RPL; r++) {
        int gi = row0 + r;
        bool ok = cok && gi >= 0 && gi < NXY;
        v2f kv = {0.f,0.f}, qv = {0.f,0.f}, cv = {0.f,0.f}, pv = {0.f,0.f};
        if (ok) {
            int idx = gi * NXY + gj;
            kv = *(const v2f*)(kg + idx);
            qv = *(const v2f*)(qg + idx);
            cv = *(const v2f*)(curg + idx);
            pv = *(const v2f*)(prvg + idx);
        }
        yc[r] = cv; yp[r] = pv; Ka[r] = kv; Qa[r] = qv;
        // out-of-domain: K=Q=0 -> yn = c = 0 forever  ✓
    }

    // source (40,96): window col 96-J0 (112 for cj0, 16 for cj1) - always even
    int sr = 40 - I0, sc = 96 - J0;
    bool wave_src = (sr >= RPL * w) && (sr < RPL * w + RPL);
    int src_rl = sr - RPL * w;
    float srcm = (2 * l == sc) ? 1.f : 0.f;

    // probes (160,{48,96,144}): row 160 -> bi==26, window row 21 (wave 4, r=1)
    int pcl = 2 * l + J0;             // this lane's global .x column
    bool wave_prb = (bi == 26) && (w == 4);
    const int prb_rl = 1;
    bool is_prb = (cj == 0) ? (pcl == 48) : (pcl == 96 || pcl == 144);
    float prbm = is_prb ? 1.f : 0.f;
    float pacc = 0.f;

    v2f uph, dnh;

// row update: yn = c + Q*(p-c) + K*(S-4c) — packed fp32, 2 DPP per 2 cells
#define ROWC(CUR, PRV, rr_, UP, DN, XSV, YN) do {                              \
    v2f cv = CUR[rr_];                                                         \
    float lf0 = dpp_up1(cv.y);                                                 \
    float rt1 = dpp_dn1(cv.x);                                                 \
    v2f h = (v2f){lf0, rt1} + __builtin_shufflevector(cv, cv, 1, 0);           \
    v2f S = ((UP) + (DN)) + h;                                                 \
    YN = cv + Qa[rr_] * (PRV[rr_] - cv) + Ka[rr_] * (S - 4.0f * cv);           \
    if (wave_src && (rr_) == src_rl) YN.x += srcm * (XSV);                     \
    if (wave_prb && (rr_) == prb_rl) { float q = prbm * YN.x; pacc += q * YN.x; } \
} while (0)

// boundary rows first (early LDS write), interior hides it; ghost read after
// barrier is first used next step
#define STEP(CUR, PRV, PH, SIDX) do {                                          \
    v2f t0, t4;                                                                \
    ROWC(CUR, PRV, 0, uph,    CUR[1], xv[SIDX], t0);                           \
    ROWC(CUR, PRV, 4, CUR[3], dnh,    xv[SIDX], t4);                           \
    hb[PH][0][w + 1][l] = t0;                                                  \
    hb[PH][1][w + 1][l] = t4;                                                  \
    PRV[0] = t0; PRV[4] = t4;                                                  \
    _Pragma("unroll")                                                          \
    for (int r = 1; r <= 3; r++) {                                             \
        v2f y;                                                                 \
        ROWC(CUR, PRV, r, CUR[r - 1], CUR[r + 1], xv[SIDX], y);                \
        PRV[r] = y;                                                            \
    }                                                                          \
    __syncthreads();                                                           \
    uph = hb[PH][1][w][l];                                                     \
    dnh = hb[PH][0][w + 2][l];                                                 \
} while (0)

    // prologue halo exchange (parity 0)
    hb[0][0][w + 1][l] = yc[0];
    hb[0][1][w + 1][l] = yc[4];
    __syncthreads();
    uph = hb[0][1][w][l];
    dnh = hb[0][0][w + 2][l];

#pragma unroll
    for (int s2 = 0; s2 < TCH / 2; s2++) {
        STEP(yc, yp, 1, 2 * s2);        // new cur -> yp, writes hb[1]
        STEP(yp, yc, 0, 2 * s2 + 1);    // new cur -> yc, writes hb[0]
    }
#undef STEP
#undef ROWC
    // yc = y(t_end), yp = y(t_end-1); clean on window rows [16,24), cols [16,112)

    // store out-tile: rows [6bi, 6bi+6) (window rows [17,23)), lanes 8..55
#pragma unroll
    for (int r = 0; r < RPL; r++) {
        int gi = row0 + r;
        if (gi >= OUTR * bi && gi < OUTR * bi + OUTR && l >= 8 && l < 56) {
            int idx = gi * NXY + gj;
            *(v2f*)(ncurg + idx) = yc[r];
            *(v2f*)(nprvg + idx) = yp[r];
        }
    }
    // unique writer per (b,pid): bi==26, owning col-tile, one lane per probe
    if (wave_prb && is_prb)
        ws[I_OFF + b * 3 + (pcl / 48 - 1)] += pacc;
}

__global__ void final_k(const float* __restrict__ ws, float* __restrict__ out) {
    int t = threadIdx.x;
    if (t < 12) {
        const float* I = ws + I_OFF;
        int b = t / 3;
        float s = I[3 * b] + I[3 * b + 1] + I[3 * b + 2];
        out[t] = I[t] / s;
    }
}

extern "C" void kernel_launch(void* const* d_in, const int* in_sizes, int n_in,
                              void* d_out, int out_size, void* d_ws, size_t ws_size,
                              hipStream_t stream) {
    const float* x   = (const float*)d_in[0];   // (4,256) fp32
    const float* rho = (const float*)d_in[1];   // (192,192) fp32
    float* ws  = (float*)d_ws;
    float* out = (float*)d_out;

    setup_k<<<256, 256, 0, stream>>>(rho, ws);
    for (int c = 0; c < NCHUNK; c++)
        chunk_k<<<NBLKS, TPB, 0, stream>>>(x, ws, c);
    final_k<<<1, 64, 0, stream>>>(ws, out);
}